// Round 1
// baseline (676.926 us; speedup 1.0000x reference)
//
#include <hip/hip_runtime.h>
#include <hip/hip_bf16.h>
#include <math.h>

#define N_NODES 4096
#define N_EDGES 16384
#define D_IN 128
#define HID 1024

typedef short s8v __attribute__((ext_vector_type(8)));
typedef float f4v __attribute__((ext_vector_type(4)));

// ---------- helpers ----------
__device__ __forceinline__ unsigned short f2b(float v) {
    union { float f; unsigned int u; } c; c.f = v;
    unsigned int u = c.u + 0x7fffu + ((c.u >> 16) & 1u);  // round-to-nearest-even
    return (unsigned short)(u >> 16);
}
__device__ __forceinline__ float b2f(unsigned short b) {
    union { unsigned int u; float f; } c; c.u = ((unsigned int)b) << 16;
    return c.f;
}

// ---------- kernel 1: one-hot row -> index ----------
// grid: 2*N_EDGES blocks of 256 threads; block b<E scans Ro row b -> src[b],
// else Ri row (b-E) -> dst[b-E]. 4096 floats per row = 1024 float4.
__global__ void extract_idx(const float* __restrict__ Ro, const float* __restrict__ Ri,
                            int* __restrict__ src, int* __restrict__ dst) {
    int b = blockIdx.x;
    const float* rowp;
    int* outp;
    if (b < N_EDGES) { rowp = Ro + (size_t)b * N_NODES; outp = src + b; }
    else             { rowp = Ri + (size_t)(b - N_EDGES) * N_NODES; outp = dst + (b - N_EDGES); }
    int t = threadIdx.x;
    const float4* r4 = (const float4*)rowp;
#pragma unroll
    for (int i = 0; i < 4; ++i) {
        int c = t + i * 256;
        float4 v = r4[c];
        int base = c * 4;
        if (v.x != 0.0f) *outp = base;
        if (v.y != 0.0f) *outp = base + 1;
        if (v.z != 0.0f) *outp = base + 2;
        if (v.w != 0.0f) *outp = base + 3;
    }
}

// ---------- kernel 2: eH = e*H ; xf[:,128:256] = H ----------
__global__ void eh_fill(const float* __restrict__ H, const float* __restrict__ e,
                        float* __restrict__ eH, float* __restrict__ xf) {
    int i = blockIdx.x * 256 + threadIdx.x;        // < N_NODES*D_IN
    int n = i >> 7, d = i & 127;
    float h = H[i];
    eH[i] = e[n] * h;
    xf[(size_t)n * 384 + 128 + d] = h;
}

// ---------- kernel 3: scatter-add Ho / Hi ----------
// thread per (edge, feature). Ho[dst] += eH[src]; Hi[src] += eH[dst].
__global__ void scatter(const int* __restrict__ src, const int* __restrict__ dst,
                        const float* __restrict__ eH, float* __restrict__ xf) {
    int i = blockIdx.x * 256 + threadIdx.x;        // < N_EDGES*128
    int ed = i >> 7, j = i & 127;
    int s = src[ed], d = dst[ed];
    atomicAdd(&xf[(size_t)d * 384 + j],       eH[(size_t)s * 128 + j]);
    atomicAdd(&xf[(size_t)s * 384 + 256 + j], eH[(size_t)d * 128 + j]);
}

// ---------- kernel 4: f32 -> bf16 convert ----------
__global__ void cvt_f2b(const float* __restrict__ x, unsigned short* __restrict__ y, int n) {
    int i = blockIdx.x * 256 + threadIdx.x;
    if (i < n) y[i] = f2b(x[i]);
}

// ---------- kernel 5: weight transpose + convert: W[K][N] f32 -> WT[N][K] bf16 ----------
__global__ void wtrans(const float* __restrict__ W, unsigned short* __restrict__ WT,
                       int K, int N) {
    int i = blockIdx.x * 256 + threadIdx.x;
    if (i >= K * N) return;
    int n = i / K, k = i - n * K;
    WT[i] = f2b(W[(size_t)k * N + n]);
}

// ---------- kernel 6: bf16 MFMA GEMM, C = tanh(A @ BT^T + bias), bf16 out ----------
// A [M,K] bf16 row-major, BT [N,K] bf16 row-major. Block tile 128x128, BK=32.
// 256 threads = 4 waves (2x2), each wave 64x64 via 4x4 mfma_f32_16x16x32_bf16.
#define BM 128
#define BN 128
#define BK 32
#define LDA 40  // padded LDS row (elements); 40*2=80B keeps b128 16B-aligned, <=2-way bank conflict
__global__ __launch_bounds__(256)
void gemm_tanh(const unsigned short* __restrict__ A, const unsigned short* __restrict__ BT,
               const float* __restrict__ bias, unsigned short* __restrict__ C,
               int M, int N, int K) {
    __shared__ unsigned short As[BM * LDA];
    __shared__ unsigned short Bs[BN * LDA];
    int t = threadIdx.x;
    int l = t & 63, w = t >> 6;
    int wm = w >> 1, wn = w & 1;
    int q = l >> 4, r16 = l & 15;
    int m0 = blockIdx.y * BM, n0 = blockIdx.x * BN;

    f4v acc[4][4] = {};

    for (int k0 = 0; k0 < K; k0 += BK) {
        __syncthreads();
        // stage: 128x32 tile = 512 chunks of 8 elems; 2 chunks/thread/matrix
#pragma unroll
        for (int i = 0; i < 2; ++i) {
            int c = i * 256 + t;
            int row = c >> 2, ko = (c & 3) * 8;
            *(s8v*)&As[row * LDA + ko] = *(const s8v*)&A[(size_t)(m0 + row) * K + k0 + ko];
            *(s8v*)&Bs[row * LDA + ko] = *(const s8v*)&BT[(size_t)(n0 + row) * K + k0 + ko];
        }
        __syncthreads();
        s8v a[4], b[4];
#pragma unroll
        for (int mi = 0; mi < 4; ++mi)
            a[mi] = *(const s8v*)&As[(wm * 64 + mi * 16 + r16) * LDA + q * 8];
#pragma unroll
        for (int ni = 0; ni < 4; ++ni)
            b[ni] = *(const s8v*)&Bs[(wn * 64 + ni * 16 + r16) * LDA + q * 8];
#pragma unroll
        for (int mi = 0; mi < 4; ++mi)
#pragma unroll
            for (int ni = 0; ni < 4; ++ni)
                acc[mi][ni] = __builtin_amdgcn_mfma_f32_16x16x32_bf16(a[mi], b[ni], acc[mi][ni], 0, 0, 0);
    }

    // epilogue: C/D layout col=lane&15, row=(lane>>4)*4+reg
#pragma unroll
    for (int mi = 0; mi < 4; ++mi) {
#pragma unroll
        for (int ni = 0; ni < 4; ++ni) {
            int col = n0 + wn * 64 + ni * 16 + r16;
            float bv = bias[col];
#pragma unroll
            for (int r = 0; r < 4; ++r) {
                int row = m0 + wm * 64 + mi * 16 + q * 4 + r;
                float v = tanhf(acc[mi][ni][r] + bv);
                C[(size_t)row * N + col] = f2b(v);
            }
        }
    }
}

// ---------- kernel 7: final layer, N=1: out = sigmoid(h4 @ w5 + b5) ----------
// one wave per row; lane l covers cols l*4..l*4+3 of 256.
__global__ void layer5(const unsigned short* __restrict__ h4, const unsigned short* __restrict__ w5,
                       const float* __restrict__ b5, float* __restrict__ out) {
    int row = blockIdx.x * 4 + (threadIdx.x >> 6);
    int l = threadIdx.x & 63;
    const ushort4 hv = *(const ushort4*)(h4 + (size_t)row * 256 + l * 4);
    const ushort4 wv = *(const ushort4*)(w5 + l * 4);
    float s = b2f(hv.x) * b2f(wv.x) + b2f(hv.y) * b2f(wv.y)
            + b2f(hv.z) * b2f(wv.z) + b2f(hv.w) * b2f(wv.w);
#pragma unroll
    for (int off = 32; off > 0; off >>= 1) s += __shfl_down(s, off);
    if (l == 0) out[row] = 1.0f / (1.0f + expf(-(s + b5[0])));
}

extern "C" void kernel_launch(void* const* d_in, const int* in_sizes, int n_in,
                              void* d_out, int out_size, void* d_ws, size_t ws_size,
                              hipStream_t stream) {
    const float* H  = (const float*)d_in[0];
    const float* Ro = (const float*)d_in[1];
    const float* Ri = (const float*)d_in[2];
    const float* e  = (const float*)d_in[3];
    const float* W1 = (const float*)d_in[4];  const float* b1 = (const float*)d_in[5];
    const float* W2 = (const float*)d_in[6];  const float* b2 = (const float*)d_in[7];
    const float* W3 = (const float*)d_in[8];  const float* b3 = (const float*)d_in[9];
    const float* W4 = (const float*)d_in[10]; const float* b4 = (const float*)d_in[11];
    const float* W5 = (const float*)d_in[12]; const float* b5 = (const float*)d_in[13];
    float* out = (float*)d_out;

    // ---- workspace carve-out (256B aligned) ----
    char* p = (char*)d_ws;
    auto alloc = [&](size_t bytes) -> void* {
        void* r = (void*)p;
        p += (bytes + 255) & ~(size_t)255;
        return r;
    };
    int*   src = (int*)  alloc(N_EDGES * 4);
    int*   dst = (int*)  alloc(N_EDGES * 4);
    float* eH  = (float*)alloc((size_t)N_NODES * D_IN * 4);          // 2 MB
    float* xf  = (float*)alloc((size_t)N_NODES * 384 * 4);           // 6 MB
    unsigned short* xb  = (unsigned short*)alloc((size_t)N_NODES * 384 * 2);
    unsigned short* h1  = (unsigned short*)alloc((size_t)N_NODES * HID * 2);
    unsigned short* h2  = (unsigned short*)alloc((size_t)N_NODES * HID * 2);
    unsigned short* h3  = (unsigned short*)alloc((size_t)N_NODES * (HID / 2) * 2);
    unsigned short* h4  = (unsigned short*)alloc((size_t)N_NODES * (HID / 4) * 2);
    unsigned short* wt1 = (unsigned short*)alloc((size_t)HID * 384 * 2);
    unsigned short* wt2 = (unsigned short*)alloc((size_t)HID * HID * 2);
    unsigned short* wt3 = (unsigned short*)alloc((size_t)(HID / 2) * HID * 2);
    unsigned short* wt4 = (unsigned short*)alloc((size_t)(HID / 4) * (HID / 2) * 2);
    unsigned short* wt5 = (unsigned short*)alloc((size_t)(HID / 4) * 2);

    // 0) zero the x buffer (Ho/Hi accumulators); middle columns overwritten by eh_fill
    hipMemsetAsync(xf, 0, (size_t)N_NODES * 384 * 4, stream);

    // 1) indices from one-hot rows (the 512 MB scan — the structural floor)
    extract_idx<<<2 * N_EDGES, 256, 0, stream>>>(Ro, Ri, src, dst);

    // 2) eH and H placement
    eh_fill<<<(N_NODES * D_IN) / 256, 256, 0, stream>>>(H, e, eH, xf);

    // 3) scatter-add Ho / Hi
    scatter<<<(N_EDGES * 128) / 256, 256, 0, stream>>>(src, dst, eH, xf);

    // 4) x -> bf16
    cvt_f2b<<<(N_NODES * 384) / 256, 256, 0, stream>>>(xf, xb, N_NODES * 384);

    // 5) weights -> transposed bf16
    wtrans<<<(384 * HID + 255) / 256, 256, 0, stream>>>(W1, wt1, 384, HID);
    wtrans<<<(HID * HID + 255) / 256, 256, 0, stream>>>(W2, wt2, HID, HID);
    wtrans<<<(HID * (HID / 2) + 255) / 256, 256, 0, stream>>>(W3, wt3, HID, HID / 2);
    wtrans<<<((HID / 2) * (HID / 4) + 255) / 256, 256, 0, stream>>>(W4, wt4, HID / 2, HID / 4);
    wtrans<<<((HID / 4) + 255) / 256, 256, 0, stream>>>(W5, wt5, HID / 4, 1);

    // 6) MLP
    gemm_tanh<<<dim3(HID / BN, N_NODES / BM), 256, 0, stream>>>(xb, wt1, b1, h1, N_NODES, HID, 384);
    gemm_tanh<<<dim3(HID / BN, N_NODES / BM), 256, 0, stream>>>(h1, wt2, b2, h2, N_NODES, HID, HID);
    gemm_tanh<<<dim3((HID / 2) / BN, N_NODES / BM), 256, 0, stream>>>(h2, wt3, b3, h3, N_NODES, HID / 2, HID);
    gemm_tanh<<<dim3((HID / 4) / BN, N_NODES / BM), 256, 0, stream>>>(h3, wt4, b4, h4, N_NODES, HID / 4, HID / 2);

    // 7) final sigmoid layer
    layer5<<<N_NODES / 4, 256, 0, stream>>>(h4, wt5, b5, out);
}

// Round 2
// 597.285 us; speedup vs baseline: 1.1333x; 1.1333x over previous
//
#include <hip/hip_runtime.h>
#include <hip/hip_bf16.h>
#include <math.h>

#define N_NODES 4096
#define N_EDGES 16384
#define D_IN 128
#define HID 1024

typedef short s8v __attribute__((ext_vector_type(8)));
typedef float f4v __attribute__((ext_vector_type(4)));

// ---------- helpers ----------
__device__ __forceinline__ unsigned short f2b(float v) {
    union { float f; unsigned int u; } c; c.f = v;
    unsigned int u = c.u + 0x7fffu + ((c.u >> 16) & 1u);  // round-to-nearest-even
    return (unsigned short)(u >> 16);
}
__device__ __forceinline__ float b2f(unsigned short b) {
    union { unsigned int u; float f; } c; c.u = ((unsigned int)b) << 16;
    return c.f;
}
// async global->LDS, 16B per lane. LDS dest is wave-uniform base + lane*16;
// we pass per-lane &lds[chunk*8] where chunk = uniform + lane, which satisfies it.
__device__ __forceinline__ void glds16(const unsigned short* g, unsigned short* l) {
    __builtin_amdgcn_global_load_lds(
        (const __attribute__((address_space(1))) void*)g,
        (__attribute__((address_space(3))) void*)l, 16, 0, 0);
}

// ---------- kernel 1: one-hot row -> index, early-exit chunked scan ----------
// block b < E scans Ro row b -> src[b], else Ri row (b-E) -> dst[b-E].
// 4 chunks of 1024 cols; expected 2.5 chunks read => ~62.5% of 512 MB.
__global__ void extract_idx(const float* __restrict__ Ro, const float* __restrict__ Ri,
                            int* __restrict__ src, int* __restrict__ dst) {
    __shared__ int found;
    int b = blockIdx.x;
    const float* rowp;
    int* outp;
    if (b < N_EDGES) { rowp = Ro + (size_t)b * N_NODES; outp = src + b; }
    else             { rowp = Ri + (size_t)(b - N_EDGES) * N_NODES; outp = dst + (b - N_EDGES); }
    int t = threadIdx.x;
    if (t == 0) found = 0;
    __syncthreads();
    const float4* r4 = (const float4*)rowp;
    for (int i = 0; i < 4; ++i) {
        int c = t + i * 256;
        float4 v = r4[c];
        if (v.x != 0.0f || v.y != 0.0f || v.z != 0.0f || v.w != 0.0f) {
            int idx = c * 4 + (v.x != 0.0f ? 0 : v.y != 0.0f ? 1 : v.z != 0.0f ? 2 : 3);
            *outp = idx;
            found = 1;
        }
        __syncthreads();
        if (found) break;   // uniform after barrier; flag is monotone 0->1
    }
}

// ---------- kernel 2: scatter-add Ho / Hi directly from H,e ----------
// xf layout [N_NODES][256]: cols 0..127 = Ho, 128..255 = Hi.
__global__ void scatter(const int* __restrict__ src, const int* __restrict__ dst,
                        const float* __restrict__ H, const float* __restrict__ e,
                        float* __restrict__ xf) {
    int i = blockIdx.x * 256 + threadIdx.x;        // < N_EDGES*128
    int ed = i >> 7, j = i & 127;
    int s = src[ed], d = dst[ed];
    atomicAdd(&xf[(size_t)d * 256 + j],       e[s] * H[(size_t)s * 128 + j]);
    atomicAdd(&xf[(size_t)s * 256 + 128 + j], e[d] * H[(size_t)d * 128 + j]);
}

// ---------- kernel 3: assemble x = [Ho | H | Hi] as bf16 [N_NODES][384] ----------
__global__ void cvt_x(const float* __restrict__ xf, const float* __restrict__ H,
                      unsigned short* __restrict__ xb) {
    int n = blockIdx.x, c = threadIdx.x;   // 384 threads
    float v;
    if (c < 128)       v = xf[(size_t)n * 256 + c];           // Ho
    else if (c < 256)  v = H[(size_t)n * 128 + c - 128];      // H
    else               v = xf[(size_t)n * 256 + c - 128];     // Hi
    xb[(size_t)n * 384 + c] = f2b(v);
}

// ---------- kernel 4: fused weight transpose+convert, all 5 weights ----------
// W[K][N] f32 -> WT[N][K] bf16, 32x32 LDS tiles, coalesced both sides.
__global__ void wtrans_all(const float* __restrict__ W1, unsigned short* __restrict__ wt1,
                           const float* __restrict__ W2, unsigned short* __restrict__ wt2,
                           const float* __restrict__ W3, unsigned short* __restrict__ wt3,
                           const float* __restrict__ W4, unsigned short* __restrict__ wt4,
                           const float* __restrict__ W5, unsigned short* __restrict__ wt5) {
    int b = blockIdx.x, t = threadIdx.x;
    const float* W; unsigned short* WT; int K, N, tb;
    if (b < 384)       { W = W1; WT = wt1; K = 384;  N = 1024; tb = b; }
    else if (b < 1408) { W = W2; WT = wt2; K = 1024; N = 1024; tb = b - 384; }
    else if (b < 1920) { W = W3; WT = wt3; K = 1024; N = 512;  tb = b - 1408; }
    else if (b < 2048) { W = W4; WT = wt4; K = 512;  N = 256;  tb = b - 1920; }
    else { wt5[t] = f2b(W5[t]); return; }  // W5: [256,1] -> flat copy

    __shared__ float tile[32][33];
    int ntx = N >> 5;
    int tk = tb / ntx, tn = tb - tk * ntx;
    int tr = t >> 5, tc = t & 31;          // 8 rows x 32 cols per pass, 4 passes
#pragma unroll
    for (int i = 0; i < 4; ++i)
        tile[tr + i * 8][tc] = W[(size_t)(tk * 32 + tr + i * 8) * N + tn * 32 + tc];
    __syncthreads();
#pragma unroll
    for (int i = 0; i < 4; ++i)
        WT[(size_t)(tn * 32 + tr + i * 8) * K + tk * 32 + tc] = f2b(tile[tc][tr + i * 8]);
}

// ---------- kernel 5: bf16 MFMA GEMM (m97-style), C = tanh(A @ BT^T + bias) ----------
// A [M,K] bf16 rm, BT [N,K] bf16 rm. BK=32, 256 thr = 4 waves 2x2,
// wave tile (BM/2)x(BN/2) via mfma_f32_16x16x32_bf16. Unpadded LDS (glds reqt);
// b128 fragment reads spread uniformly over all 32 banks (8-cy floor, no penalty).
template<int BM, int BN>
__global__ __launch_bounds__(256)
void gemm_tanh(const unsigned short* __restrict__ A, const unsigned short* __restrict__ BT,
               const float* __restrict__ bias, unsigned short* __restrict__ C,
               int M, int N, int K) {
    constexpr int BK = 32;
    constexpr int MI = BM / 32;            // mfma m-tiles per wave
    constexpr int NI = BN / 32;            // mfma n-tiles per wave
    constexpr int AITER = BM / 64;         // glds wave-iterations for A tile
    constexpr int BITER = BN / 64;
    __shared__ unsigned short As[BM * BK];
    __shared__ unsigned short Bs[BN * BK];
    int t = threadIdx.x;
    int l = t & 63, w = t >> 6;
    int wm = w >> 1, wn = w & 1;
    int q = l >> 4, r16 = l & 15;
    int m0 = blockIdx.y * BM, n0 = blockIdx.x * BN;

    f4v acc[MI][NI] = {};

    for (int k0 = 0; k0 < K; k0 += BK) {
        __syncthreads();
        // chunk c (16B) <-> row = c>>2, ko = (c&3)*8 ; lds byte off = c*16
#pragma unroll
        for (int i = 0; i < AITER; ++i) {
            int c = (i * 4 + w) * 64 + l;
            int row = c >> 2, ko = (c & 3) * 8;
            glds16(&A[(size_t)(m0 + row) * K + k0 + ko], &As[c * 8]);
        }
#pragma unroll
        for (int i = 0; i < BITER; ++i) {
            int c = (i * 4 + w) * 64 + l;
            int row = c >> 2, ko = (c & 3) * 8;
            glds16(&BT[(size_t)(n0 + row) * K + k0 + ko], &Bs[c * 8]);
        }
        __syncthreads();
        s8v a[MI], b[NI];
#pragma unroll
        for (int mi = 0; mi < MI; ++mi)
            a[mi] = *(const s8v*)&As[(wm * (BM / 2) + mi * 16 + r16) * BK + q * 8];
#pragma unroll
        for (int ni = 0; ni < NI; ++ni)
            b[ni] = *(const s8v*)&Bs[(wn * (BN / 2) + ni * 16 + r16) * BK + q * 8];
#pragma unroll
        for (int mi = 0; mi < MI; ++mi)
#pragma unroll
            for (int ni = 0; ni < NI; ++ni)
                acc[mi][ni] = __builtin_amdgcn_mfma_f32_16x16x32_bf16(a[mi], b[ni], acc[mi][ni], 0, 0, 0);
    }

    // epilogue: C/D layout col=lane&15, row=(lane>>4)*4+reg
#pragma unroll
    for (int mi = 0; mi < MI; ++mi) {
#pragma unroll
        for (int ni = 0; ni < NI; ++ni) {
            int col = n0 + wn * (BN / 2) + ni * 16 + r16;
            float bv = bias[col];
#pragma unroll
            for (int r = 0; r < 4; ++r) {
                int row = m0 + wm * (BM / 2) + mi * 16 + q * 4 + r;
                C[(size_t)row * N + col] = f2b(tanhf(acc[mi][ni][r] + bv));
            }
        }
    }
}

// ---------- kernel 6: final layer, N=1: out = sigmoid(h4 @ w5 + b5) ----------
__global__ void layer5(const unsigned short* __restrict__ h4, const unsigned short* __restrict__ w5,
                       const float* __restrict__ b5, float* __restrict__ out) {
    int row = blockIdx.x * 4 + (threadIdx.x >> 6);
    int l = threadIdx.x & 63;
    const ushort4 hv = *(const ushort4*)(h4 + (size_t)row * 256 + l * 4);
    const ushort4 wv = *(const ushort4*)(w5 + l * 4);
    float s = b2f(hv.x) * b2f(wv.x) + b2f(hv.y) * b2f(wv.y)
            + b2f(hv.z) * b2f(wv.z) + b2f(hv.w) * b2f(wv.w);
#pragma unroll
    for (int off = 32; off > 0; off >>= 1) s += __shfl_down(s, off);
    if (l == 0) out[row] = 1.0f / (1.0f + expf(-(s + b5[0])));
}

extern "C" void kernel_launch(void* const* d_in, const int* in_sizes, int n_in,
                              void* d_out, int out_size, void* d_ws, size_t ws_size,
                              hipStream_t stream) {
    const float* H  = (const float*)d_in[0];
    const float* Ro = (const float*)d_in[1];
    const float* Ri = (const float*)d_in[2];
    const float* e  = (const float*)d_in[3];
    const float* W1 = (const float*)d_in[4];  const float* b1 = (const float*)d_in[5];
    const float* W2 = (const float*)d_in[6];  const float* b2 = (const float*)d_in[7];
    const float* W3 = (const float*)d_in[8];  const float* b3 = (const float*)d_in[9];
    const float* W4 = (const float*)d_in[10]; const float* b4 = (const float*)d_in[11];
    const float* W5 = (const float*)d_in[12]; const float* b5 = (const float*)d_in[13];
    float* out = (float*)d_out;

    // ---- workspace carve-out (256B aligned) ----
    char* p = (char*)d_ws;
    auto alloc = [&](size_t bytes) -> void* {
        void* r = (void*)p;
        p += (bytes + 255) & ~(size_t)255;
        return r;
    };
    int*   src = (int*)  alloc(N_EDGES * 4);
    int*   dst = (int*)  alloc(N_EDGES * 4);
    float* xf  = (float*)alloc((size_t)N_NODES * 256 * 4);           // [Ho|Hi] accum, 4 MB
    unsigned short* xb  = (unsigned short*)alloc((size_t)N_NODES * 384 * 2);
    unsigned short* h1  = (unsigned short*)alloc((size_t)N_NODES * HID * 2);
    unsigned short* h2  = (unsigned short*)alloc((size_t)N_NODES * HID * 2);
    unsigned short* h3  = (unsigned short*)alloc((size_t)N_NODES * (HID / 2) * 2);
    unsigned short* h4  = (unsigned short*)alloc((size_t)N_NODES * (HID / 4) * 2);
    unsigned short* wt1 = (unsigned short*)alloc((size_t)HID * 384 * 2);
    unsigned short* wt2 = (unsigned short*)alloc((size_t)HID * HID * 2);
    unsigned short* wt3 = (unsigned short*)alloc((size_t)(HID / 2) * HID * 2);
    unsigned short* wt4 = (unsigned short*)alloc((size_t)(HID / 4) * (HID / 2) * 2);
    unsigned short* wt5 = (unsigned short*)alloc((size_t)(HID / 4) * 2);

    // 0) zero the Ho/Hi accumulator
    hipMemsetAsync(xf, 0, (size_t)N_NODES * 256 * 4, stream);

    // 1) indices from one-hot rows (early-exit scan, ~320 MB expected)
    extract_idx<<<2 * N_EDGES, 256, 0, stream>>>(Ro, Ri, src, dst);

    // 2) weight transpose+convert (independent of 1; same stream anyway)
    wtrans_all<<<2049, 256, 0, stream>>>(W1, wt1, W2, wt2, W3, wt3, W4, wt4, W5, wt5);

    // 3) scatter-add Ho/Hi from H,e
    scatter<<<(N_EDGES * 128) / 256, 256, 0, stream>>>(src, dst, H, e, xf);

    // 4) assemble x as bf16
    cvt_x<<<N_NODES, 384, 0, stream>>>(xf, H, xb);

    // 5) MLP: tile (128,64) for >=256-512 blocks; L4 uses (64,64)
    gemm_tanh<128, 64><<<dim3(HID / 64, N_NODES / 128), 256, 0, stream>>>(xb, wt1, b1, h1, N_NODES, HID, 384);
    gemm_tanh<128, 64><<<dim3(HID / 64, N_NODES / 128), 256, 0, stream>>>(h1, wt2, b2, h2, N_NODES, HID, HID);
    gemm_tanh<128, 64><<<dim3((HID / 2) / 64, N_NODES / 128), 256, 0, stream>>>(h2, wt3, b3, h3, N_NODES, HID / 2, HID);
    gemm_tanh<64, 64><<<dim3((HID / 4) / 64, N_NODES / 64), 256, 0, stream>>>(h3, wt4, b4, h4, N_NODES, HID / 4, HID / 2);

    // 6) final sigmoid layer
    layer5<<<N_NODES / 4, 256, 0, stream>>>(h4, wt5, b5, out);
}

// Round 3
// 594.466 us; speedup vs baseline: 1.1387x; 1.0047x over previous
//
#include <hip/hip_runtime.h>
#include <hip/hip_bf16.h>
#include <math.h>

#define N_NODES 4096
#define N_EDGES 16384
#define D_IN 128
#define HID 1024

typedef short s8v __attribute__((ext_vector_type(8)));
typedef float f4v __attribute__((ext_vector_type(4)));

// ---------- helpers ----------
__device__ __forceinline__ unsigned short f2b(float v) {
    union { float f; unsigned int u; } c; c.f = v;
    unsigned int u = c.u + 0x7fffu + ((c.u >> 16) & 1u);  // round-to-nearest-even
    return (unsigned short)(u >> 16);
}
__device__ __forceinline__ float b2f(unsigned short b) {
    union { unsigned int u; float f; } c; c.u = ((unsigned int)b) << 16;
    return c.f;
}
// async global->LDS, 16B per lane. LDS dest must be wave-uniform base + lane*16;
// chunk index c = uniform + lane satisfies this (lds off = c*16).
__device__ __forceinline__ void glds16(const unsigned short* g, unsigned short* l) {
    __builtin_amdgcn_global_load_lds(
        (const __attribute__((address_space(1))) void*)g,
        (__attribute__((address_space(3))) void*)l, 16, 0, 0);
}

// ---------- kernel 1: one-hot row -> index, wave-per-row ballot early-exit ----------
// wave gw scans row gw (Ro rows then Ri rows), 256 cols (64 lanes x float4) per iter.
// Expected ~8.5/16 iters => ~272 MB total read (vs 512 MB full scan).
__global__ void extract_idx(const float* __restrict__ Ro, const float* __restrict__ Ri,
                            int* __restrict__ src, int* __restrict__ dst) {
    int gw = (blockIdx.x * 256 + threadIdx.x) >> 6;
    int l = threadIdx.x & 63;
    const float* rowp;
    int* outp;
    if (gw < N_EDGES) { rowp = Ro + (size_t)gw * N_NODES; outp = src + gw; }
    else              { rowp = Ri + (size_t)(gw - N_EDGES) * N_NODES; outp = dst + (gw - N_EDGES); }
    const float4* r4 = (const float4*)rowp;
    for (int it = 0; it < 16; ++it) {
        float4 v = r4[it * 64 + l];
        bool hit = (v.x != 0.0f) | (v.y != 0.0f) | (v.z != 0.0f) | (v.w != 0.0f);
        unsigned long long m = __ballot(hit);
        if (m) {  // wave-uniform
            if (hit && l == (__ffsll((long long)m) - 1)) {
                int base = (it * 64 + l) * 4;
                *outp = base + (v.x != 0.0f ? 0 : v.y != 0.0f ? 1 : v.z != 0.0f ? 2 : 3);
            }
            break;
        }
    }
}

// ---------- kernel 2: histogram of dst (out-lists) and src (in-lists) ----------
__global__ void hist(const int* __restrict__ src, const int* __restrict__ dst,
                     int* __restrict__ cnt_o, int* __restrict__ cnt_i) {
    int e = blockIdx.x * 256 + threadIdx.x;   // < N_EDGES
    atomicAdd(&cnt_o[dst[e]], 1);
    atomicAdd(&cnt_i[src[e]], 1);
}

// ---------- kernel 3: exclusive prefix scan of 4096 counters (2 blocks, one per array) ----------
__global__ __launch_bounds__(1024)
void scan4096(const int* __restrict__ cnt_o, int* __restrict__ off_o, int* __restrict__ cur_o,
              const int* __restrict__ cnt_i, int* __restrict__ off_i, int* __restrict__ cur_i) {
    const int* cnt = blockIdx.x ? cnt_i : cnt_o;
    int* off = blockIdx.x ? off_i : off_o;
    int* cur = blockIdx.x ? cur_i : cur_o;
    __shared__ int part[1024];
    int t = threadIdx.x;
    int v0 = cnt[t * 4], v1 = cnt[t * 4 + 1], v2 = cnt[t * 4 + 2], v3 = cnt[t * 4 + 3];
    int sum = v0 + v1 + v2 + v3;
    part[t] = sum;
    __syncthreads();
    for (int d = 1; d < 1024; d <<= 1) {
        int x = (t >= d) ? part[t - d] : 0;
        __syncthreads();
        part[t] += x;
        __syncthreads();
    }
    int run = part[t] - sum;   // exclusive base for this thread's 4
    off[t * 4] = run;     cur[t * 4] = run;     run += v0;
    off[t * 4 + 1] = run; cur[t * 4 + 1] = run; run += v1;
    off[t * 4 + 2] = run; cur[t * 4 + 2] = run; run += v2;
    off[t * 4 + 3] = run; cur[t * 4 + 3] = run; run += v3;
    if (t == 1023) off[4096] = run;
}

// ---------- kernel 4: fill CSR edge lists ----------
__global__ void fill_csr(const int* __restrict__ src, const int* __restrict__ dst,
                         int* __restrict__ cur_o, int* __restrict__ lst_o,
                         int* __restrict__ cur_i, int* __restrict__ lst_i) {
    int e = blockIdx.x * 256 + threadIdx.x;   // < N_EDGES
    int s = src[e], d = dst[e];
    lst_o[atomicAdd(&cur_o[d], 1)] = s;
    lst_i[atomicAdd(&cur_i[s], 1)] = d;
}

// ---------- kernel 5: per-node gather-aggregate; writes x=[Ho|H|Hi] as bf16 ----------
// block = node (4096), thread = feature (128). H (2 MB) is L2-resident.
__global__ void aggregate(const int* __restrict__ off_o, const int* __restrict__ lst_o,
                          const int* __restrict__ off_i, const int* __restrict__ lst_i,
                          const float* __restrict__ H, const float* __restrict__ e,
                          unsigned short* __restrict__ xb) {
    int n = blockIdx.x, f = threadIdx.x;
    float so = 0.0f, si = 0.0f;
    int b0 = off_o[n], e0 = off_o[n + 1];
    for (int k = b0; k < e0; ++k) { int s = lst_o[k]; so += e[s] * H[(size_t)s * 128 + f]; }
    int b1 = off_i[n], e1 = off_i[n + 1];
    for (int k = b1; k < e1; ++k) { int d = lst_i[k]; si += e[d] * H[(size_t)d * 128 + f]; }
    size_t base = (size_t)n * 384;
    xb[base + f]       = f2b(so);
    xb[base + 128 + f] = f2b(H[(size_t)n * 128 + f]);
    xb[base + 256 + f] = f2b(si);
}

// ---------- kernel 6: fused weight transpose+convert, all 5 weights ----------
// W[K][N] f32 -> WT[N][K] bf16, 32x32 LDS tiles, coalesced both sides.
__global__ void wtrans_all(const float* __restrict__ W1, unsigned short* __restrict__ wt1,
                           const float* __restrict__ W2, unsigned short* __restrict__ wt2,
                           const float* __restrict__ W3, unsigned short* __restrict__ wt3,
                           const float* __restrict__ W4, unsigned short* __restrict__ wt4,
                           const float* __restrict__ W5, unsigned short* __restrict__ wt5) {
    int b = blockIdx.x, t = threadIdx.x;
    const float* W; unsigned short* WT; int K, N, tb;
    if (b < 384)       { W = W1; WT = wt1; K = 384;  N = 1024; tb = b; }
    else if (b < 1408) { W = W2; WT = wt2; K = 1024; N = 1024; tb = b - 384; }
    else if (b < 1920) { W = W3; WT = wt3; K = 1024; N = 512;  tb = b - 1408; }
    else if (b < 2048) { W = W4; WT = wt4; K = 512;  N = 256;  tb = b - 1920; }
    else { wt5[t] = f2b(W5[t]); return; }  // W5: [256,1] -> flat copy

    __shared__ float tile[32][33];
    int ntx = N >> 5;
    int tk = tb / ntx, tn = tb - tk * ntx;
    int tr = t >> 5, tc = t & 31;
#pragma unroll
    for (int i = 0; i < 4; ++i)
        tile[tr + i * 8][tc] = W[(size_t)(tk * 32 + tr + i * 8) * N + tn * 32 + tc];
    __syncthreads();
#pragma unroll
    for (int i = 0; i < 4; ++i)
        WT[(size_t)(tn * 32 + tr + i * 8) * K + tk * 32 + tc] = f2b(tile[tc][tr + i * 8]);
}

// ---------- kernel 7: bf16 MFMA GEMM (m97-style), C = tanh(A @ BT^T + bias) ----------
// A [M,K] bf16 rm, BT [N,K] bf16 rm. BK=32, 256 thr = 4 waves 2x2,
// wave tile (BM/2)x(BN/2) via mfma_f32_16x16x32_bf16. Unpadded LDS (glds reqt).
template<int BM, int BN>
__global__ __launch_bounds__(256)
void gemm_tanh(const unsigned short* __restrict__ A, const unsigned short* __restrict__ BT,
               const float* __restrict__ bias, unsigned short* __restrict__ C,
               int M, int N, int K) {
    constexpr int BK = 32;
    constexpr int MI = BM / 32;
    constexpr int NI = BN / 32;
    constexpr int AITER = BM / 64;
    constexpr int BITER = BN / 64;
    __shared__ unsigned short As[BM * BK];
    __shared__ unsigned short Bs[BN * BK];
    int t = threadIdx.x;
    int l = t & 63, w = t >> 6;
    int wm = w >> 1, wn = w & 1;
    int q = l >> 4, r16 = l & 15;
    int m0 = blockIdx.y * BM, n0 = blockIdx.x * BN;

    f4v acc[MI][NI] = {};

    for (int k0 = 0; k0 < K; k0 += BK) {
        __syncthreads();
#pragma unroll
        for (int i = 0; i < AITER; ++i) {
            int c = (i * 4 + w) * 64 + l;
            int row = c >> 2, ko = (c & 3) * 8;
            glds16(&A[(size_t)(m0 + row) * K + k0 + ko], &As[c * 8]);
        }
#pragma unroll
        for (int i = 0; i < BITER; ++i) {
            int c = (i * 4 + w) * 64 + l;
            int row = c >> 2, ko = (c & 3) * 8;
            glds16(&BT[(size_t)(n0 + row) * K + k0 + ko], &Bs[c * 8]);
        }
        __syncthreads();
        s8v a[MI], b[NI];
#pragma unroll
        for (int mi = 0; mi < MI; ++mi)
            a[mi] = *(const s8v*)&As[(wm * (BM / 2) + mi * 16 + r16) * BK + q * 8];
#pragma unroll
        for (int ni = 0; ni < NI; ++ni)
            b[ni] = *(const s8v*)&Bs[(wn * (BN / 2) + ni * 16 + r16) * BK + q * 8];
#pragma unroll
        for (int mi = 0; mi < MI; ++mi)
#pragma unroll
            for (int ni = 0; ni < NI; ++ni)
                acc[mi][ni] = __builtin_amdgcn_mfma_f32_16x16x32_bf16(a[mi], b[ni], acc[mi][ni], 0, 0, 0);
    }

    // epilogue: C/D layout col=lane&15, row=(lane>>4)*4+reg
#pragma unroll
    for (int mi = 0; mi < MI; ++mi) {
#pragma unroll
        for (int ni = 0; ni < NI; ++ni) {
            int col = n0 + wn * (BN / 2) + ni * 16 + r16;
            float bv = bias[col];
#pragma unroll
            for (int r = 0; r < 4; ++r) {
                int row = m0 + wm * (BM / 2) + mi * 16 + q * 4 + r;
                C[(size_t)row * N + col] = f2b(tanhf(acc[mi][ni][r] + bv));
            }
        }
    }
}

// ---------- kernel 8: final layer, N=1: out = sigmoid(h4 @ w5 + b5) ----------
__global__ void layer5(const unsigned short* __restrict__ h4, const unsigned short* __restrict__ w5,
                       const float* __restrict__ b5, float* __restrict__ out) {
    int row = blockIdx.x * 4 + (threadIdx.x >> 6);
    int l = threadIdx.x & 63;
    const ushort4 hv = *(const ushort4*)(h4 + (size_t)row * 256 + l * 4);
    const ushort4 wv = *(const ushort4*)(w5 + l * 4);
    float s = b2f(hv.x) * b2f(wv.x) + b2f(hv.y) * b2f(wv.y)
            + b2f(hv.z) * b2f(wv.z) + b2f(hv.w) * b2f(wv.w);
#pragma unroll
    for (int off = 32; off > 0; off >>= 1) s += __shfl_down(s, off);
    if (l == 0) out[row] = 1.0f / (1.0f + expf(-(s + b5[0])));
}

extern "C" void kernel_launch(void* const* d_in, const int* in_sizes, int n_in,
                              void* d_out, int out_size, void* d_ws, size_t ws_size,
                              hipStream_t stream) {
    const float* H  = (const float*)d_in[0];
    const float* Ro = (const float*)d_in[1];
    const float* Ri = (const float*)d_in[2];
    const float* e  = (const float*)d_in[3];
    const float* W1 = (const float*)d_in[4];  const float* b1 = (const float*)d_in[5];
    const float* W2 = (const float*)d_in[6];  const float* b2 = (const float*)d_in[7];
    const float* W3 = (const float*)d_in[8];  const float* b3 = (const float*)d_in[9];
    const float* W4 = (const float*)d_in[10]; const float* b4 = (const float*)d_in[11];
    const float* W5 = (const float*)d_in[12]; const float* b5 = (const float*)d_in[13];
    float* out = (float*)d_out;

    // ---- workspace carve-out (256B aligned) ----
    char* p = (char*)d_ws;
    auto alloc = [&](size_t bytes) -> void* {
        void* r = (void*)p;
        p += (bytes + 255) & ~(size_t)255;
        return r;
    };
    int* src   = (int*)alloc(N_EDGES * 4);
    int* dst   = (int*)alloc(N_EDGES * 4);
    int* cnt_o = (int*)alloc(N_NODES * 4);     // cnt_o, cnt_i contiguous (one memset)
    int* cnt_i = (int*)alloc(N_NODES * 4);
    int* off_o = (int*)alloc((N_NODES + 1) * 4);
    int* off_i = (int*)alloc((N_NODES + 1) * 4);
    int* cur_o = (int*)alloc(N_NODES * 4);
    int* cur_i = (int*)alloc(N_NODES * 4);
    int* lst_o = (int*)alloc(N_EDGES * 4);
    int* lst_i = (int*)alloc(N_EDGES * 4);
    unsigned short* xb  = (unsigned short*)alloc((size_t)N_NODES * 384 * 2);
    unsigned short* h1  = (unsigned short*)alloc((size_t)N_NODES * HID * 2);
    unsigned short* h2  = (unsigned short*)alloc((size_t)N_NODES * HID * 2);
    unsigned short* h3  = (unsigned short*)alloc((size_t)N_NODES * (HID / 2) * 2);
    unsigned short* h4  = (unsigned short*)alloc((size_t)N_NODES * (HID / 4) * 2);
    unsigned short* wt1 = (unsigned short*)alloc((size_t)HID * 384 * 2);
    unsigned short* wt2 = (unsigned short*)alloc((size_t)HID * HID * 2);
    unsigned short* wt3 = (unsigned short*)alloc((size_t)(HID / 2) * HID * 2);
    unsigned short* wt4 = (unsigned short*)alloc((size_t)(HID / 4) * (HID / 2) * 2);
    unsigned short* wt5 = (unsigned short*)alloc((size_t)(HID / 4) * 2);

    // 0) zero histograms (cnt_o|cnt_i contiguous after 256B-aligned carve: both 16 KB)
    hipMemsetAsync(cnt_o, 0, 2 * N_NODES * 4, stream);

    // 1) indices from one-hot rows (~272 MB expected read)
    extract_idx<<<(2 * N_EDGES) / 4, 256, 0, stream>>>(Ro, Ri, src, dst);

    // 2) weight transpose+convert (independent)
    wtrans_all<<<2049, 256, 0, stream>>>(W1, wt1, W2, wt2, W3, wt3, W4, wt4, W5, wt5);

    // 3) CSR build: hist -> scan -> fill
    hist<<<N_EDGES / 256, 256, 0, stream>>>(src, dst, cnt_o, cnt_i);
    scan4096<<<2, 1024, 0, stream>>>(cnt_o, off_o, cur_o, cnt_i, off_i, cur_i);
    fill_csr<<<N_EDGES / 256, 256, 0, stream>>>(src, dst, cur_o, lst_o, cur_i, lst_i);

    // 4) gather-aggregate -> xb = [Ho|H|Hi] bf16
    aggregate<<<N_NODES, 128, 0, stream>>>(off_o, lst_o, off_i, lst_i, H, e, xb);

    // 5) MLP
    gemm_tanh<128, 128><<<dim3(HID / 128, N_NODES / 128), 256, 0, stream>>>(xb, wt1, b1, h1, N_NODES, HID, 384);
    gemm_tanh<128, 128><<<dim3(HID / 128, N_NODES / 128), 256, 0, stream>>>(h1, wt2, b2, h2, N_NODES, HID, HID);
    gemm_tanh<128, 64><<<dim3((HID / 2) / 64, N_NODES / 128), 256, 0, stream>>>(h2, wt3, b3, h3, N_NODES, HID / 2, HID);
    gemm_tanh<64, 64><<<dim3((HID / 4) / 64, N_NODES / 64), 256, 0, stream>>>(h3, wt4, b4, h4, N_NODES, HID / 4, HID / 2);

    // 6) final sigmoid layer
    layer5<<<N_NODES / 4, 256, 0, stream>>>(h4, wt5, b5, out);
}

// Round 4
// 576.913 us; speedup vs baseline: 1.1734x; 1.0304x over previous
//
#include <hip/hip_runtime.h>
#include <hip/hip_bf16.h>
#include <math.h>

#define N_NODES 4096
#define N_EDGES 16384
#define D_IN 128
#define HID 1024

typedef short s8v __attribute__((ext_vector_type(8)));
typedef float f4v __attribute__((ext_vector_type(4)));

// ---------- helpers ----------
__device__ __forceinline__ unsigned short f2b(float v) {
    union { float f; unsigned int u; } c; c.f = v;
    unsigned int u = c.u + 0x7fffu + ((c.u >> 16) & 1u);  // round-to-nearest-even
    return (unsigned short)(u >> 16);
}
__device__ __forceinline__ float b2f(unsigned short b) {
    union { unsigned int u; float f; } c; c.u = ((unsigned int)b) << 16;
    return c.f;
}
__device__ __forceinline__ void glds16(const unsigned short* g, unsigned short* l) {
    __builtin_amdgcn_global_load_lds(
        (const __attribute__((address_space(1))) void*)g,
        (__attribute__((address_space(3))) void*)l, 16, 0, 0);
}

// ---------- kernel 1: fused index-extract + scatter ----------
// wave per edge: scan Ro[edge] and Ri[edge] rows with independent ballot
// early-exit (256-col granularity, expected ~278 MB total), then scatter
// Ho[dst] += e[src]*H[src], Hi[src] += e[dst]*H[dst] with f32 atomics.
// xf layout [N_NODES][256]: cols 0..127 = Ho, 128..255 = Hi.
__global__ void extract_scatter(const float* __restrict__ Ro, const float* __restrict__ Ri,
                                const float* __restrict__ H, const float* __restrict__ e,
                                float* __restrict__ xf) {
    int edge = (blockIdx.x * 256 + threadIdx.x) >> 6;
    int l = threadIdx.x & 63;
    const float4* ro4 = (const float4*)(Ro + (size_t)edge * N_NODES);
    const float4* ri4 = (const float4*)(Ri + (size_t)edge * N_NODES);
    int src = -1, dst = -1;
    for (int it = 0; it < 16; ++it) {
        if (src < 0) {
            float4 v = ro4[it * 64 + l];
            bool hit = (v.x != 0.0f) | (v.y != 0.0f) | (v.z != 0.0f) | (v.w != 0.0f);
            unsigned long long m = __ballot(hit);
            if (m) {
                int fl = __ffsll((long long)m) - 1;
                int idx = 0;
                if (hit) idx = (it * 64 + l) * 4 + (v.x != 0.0f ? 0 : v.y != 0.0f ? 1 : v.z != 0.0f ? 2 : 3);
                src = __shfl(idx, fl);
            }
        }
        if (dst < 0) {
            float4 v = ri4[it * 64 + l];
            bool hit = (v.x != 0.0f) | (v.y != 0.0f) | (v.z != 0.0f) | (v.w != 0.0f);
            unsigned long long m = __ballot(hit);
            if (m) {
                int fl = __ffsll((long long)m) - 1;
                int idx = 0;
                if (hit) idx = (it * 64 + l) * 4 + (v.x != 0.0f ? 0 : v.y != 0.0f ? 1 : v.z != 0.0f ? 2 : 3);
                dst = __shfl(idx, fl);
            }
        }
        if (src >= 0 && dst >= 0) break;   // wave-uniform (src/dst broadcast)
    }
    float es = e[src], ed = e[dst];
    if (l < 32) {            // Ho[dst] += es * H[src]
        int f = l * 4;
        float4 h = *(const float4*)(H + (size_t)src * 128 + f);
        float* o = xf + (size_t)dst * 256 + f;
        atomicAdd(o + 0, es * h.x); atomicAdd(o + 1, es * h.y);
        atomicAdd(o + 2, es * h.z); atomicAdd(o + 3, es * h.w);
    } else {                 // Hi[src] += ed * H[dst]
        int f = (l - 32) * 4;
        float4 h = *(const float4*)(H + (size_t)dst * 128 + f);
        float* o = xf + (size_t)src * 256 + 128 + f;
        atomicAdd(o + 0, ed * h.x); atomicAdd(o + 1, ed * h.y);
        atomicAdd(o + 2, ed * h.z); atomicAdd(o + 3, ed * h.w);
    }
}

// ---------- kernel 2: fused weight transpose+convert, all 5 weights ----------
__global__ void wtrans_all(const float* __restrict__ W1, unsigned short* __restrict__ wt1,
                           const float* __restrict__ W2, unsigned short* __restrict__ wt2,
                           const float* __restrict__ W3, unsigned short* __restrict__ wt3,
                           const float* __restrict__ W4, unsigned short* __restrict__ wt4,
                           const float* __restrict__ W5, unsigned short* __restrict__ wt5) {
    int b = blockIdx.x, t = threadIdx.x;
    const float* W; unsigned short* WT; int K, N, tb;
    if (b < 384)       { W = W1; WT = wt1; K = 384;  N = 1024; tb = b; }
    else if (b < 1408) { W = W2; WT = wt2; K = 1024; N = 1024; tb = b - 384; }
    else if (b < 1920) { W = W3; WT = wt3; K = 1024; N = 512;  tb = b - 1408; }
    else if (b < 2048) { W = W4; WT = wt4; K = 512;  N = 256;  tb = b - 1920; }
    else { wt5[t] = f2b(W5[t]); return; }

    __shared__ float tile[32][33];
    int ntx = N >> 5;
    int tk = tb / ntx, tn = tb - tk * ntx;
    int tr = t >> 5, tc = t & 31;
#pragma unroll
    for (int i = 0; i < 4; ++i)
        tile[tr + i * 8][tc] = W[(size_t)(tk * 32 + tr + i * 8) * N + tn * 32 + tc];
    __syncthreads();
#pragma unroll
    for (int i = 0; i < 4; ++i)
        WT[(size_t)(tn * 32 + tr + i * 8) * K + tk * 32 + tc] = f2b(tile[tc][tr + i * 8]);
}

// ---------- kernel 3: layer-1 GEMM, A staged from f32 (xf|H) with inline cvt ----------
// logical A[n][k], k<128: xf[n][k] (Ho); 128<=k<256: H[n][k-128]; k>=256: xf[n][k-128] (Hi).
// Each BK=32 slab lies in one region. B (wt1, bf16 [N][K]) via global_load_lds.
#define L1_BM 128
#define L1_BN 64
__global__ __launch_bounds__(256)
void gemm1(const float* __restrict__ xf, const float* __restrict__ H,
           const unsigned short* __restrict__ BT, const float* __restrict__ bias,
           unsigned short* __restrict__ C) {
    constexpr int BK = 32, K = 384, N = HID;
    constexpr int MI = L1_BM / 32, NI = L1_BN / 32;
    __shared__ unsigned short As[L1_BM * BK];
    __shared__ unsigned short Bs[L1_BN * BK];
    int t = threadIdx.x;
    int l = t & 63, w = t >> 6;
    int wm = w >> 1, wn = w & 1;
    int q = l >> 4, r16 = l & 15;
    int m0 = blockIdx.y * L1_BM, n0 = blockIdx.x * L1_BN;

    f4v acc[MI][NI] = {};

    for (int k0 = 0; k0 < K; k0 += BK) {
        __syncthreads();
        // A: 128x32 f32 -> bf16 LDS. 2 chunks of 8 cols per thread.
#pragma unroll
        for (int i = 0; i < 2; ++i) {
            int c = i * 256 + t;
            int row = c >> 2, ko = (c & 3) * 8;
            const float* sp;
            if (k0 < 128)      sp = xf + (size_t)(m0 + row) * 256 + k0 + ko;
            else if (k0 < 256) sp = H + (size_t)(m0 + row) * 128 + (k0 - 128) + ko;
            else               sp = xf + (size_t)(m0 + row) * 256 + (k0 - 128) + ko;
            float4 f0 = *(const float4*)sp, f1 = *(const float4*)(sp + 4);
            s8v pk;
            pk[0] = (short)f2b(f0.x); pk[1] = (short)f2b(f0.y);
            pk[2] = (short)f2b(f0.z); pk[3] = (short)f2b(f0.w);
            pk[4] = (short)f2b(f1.x); pk[5] = (short)f2b(f1.y);
            pk[6] = (short)f2b(f1.z); pk[7] = (short)f2b(f1.w);
            *(s8v*)&As[c * 8] = pk;
        }
        // B: 64x32 bf16 via glds (1 wave-iter: chunks w*64+l over 64 rows x 4 ko)
        {
            int c = w * 64 + l;
            int row = c >> 2, ko = (c & 3) * 8;
            glds16(&BT[(size_t)(n0 + row) * K + k0 + ko], &Bs[c * 8]);
        }
        __syncthreads();
        s8v a[MI], b[NI];
#pragma unroll
        for (int mi = 0; mi < MI; ++mi)
            a[mi] = *(const s8v*)&As[(wm * (L1_BM / 2) + mi * 16 + r16) * BK + q * 8];
#pragma unroll
        for (int ni = 0; ni < NI; ++ni)
            b[ni] = *(const s8v*)&Bs[(wn * (L1_BN / 2) + ni * 16 + r16) * BK + q * 8];
#pragma unroll
        for (int mi = 0; mi < MI; ++mi)
#pragma unroll
            for (int ni = 0; ni < NI; ++ni)
                acc[mi][ni] = __builtin_amdgcn_mfma_f32_16x16x32_bf16(a[mi], b[ni], acc[mi][ni], 0, 0, 0);
    }
#pragma unroll
    for (int mi = 0; mi < MI; ++mi)
#pragma unroll
        for (int ni = 0; ni < NI; ++ni) {
            int col = n0 + wn * (L1_BN / 2) + ni * 16 + r16;
            float bv = bias[col];
#pragma unroll
            for (int r = 0; r < 4; ++r) {
                int row = m0 + wm * (L1_BM / 2) + mi * 16 + q * 4 + r;
                C[(size_t)row * N + col] = f2b(tanhf(acc[mi][ni][r] + bv));
            }
        }
}

// ---------- kernel 4: bf16 MFMA GEMM (m97-style), C = tanh(A @ BT^T + bias) ----------
template<int BM, int BN>
__global__ __launch_bounds__(256)
void gemm_tanh(const unsigned short* __restrict__ A, const unsigned short* __restrict__ BT,
               const float* __restrict__ bias, unsigned short* __restrict__ C,
               int M, int N, int K) {
    constexpr int BK = 32;
    constexpr int MI = BM / 32, NI = BN / 32;
    constexpr int AITER = BM / 64, BITER = BN / 64;
    __shared__ unsigned short As[BM * BK];
    __shared__ unsigned short Bs[BN * BK];
    int t = threadIdx.x;
    int l = t & 63, w = t >> 6;
    int wm = w >> 1, wn = w & 1;
    int q = l >> 4, r16 = l & 15;
    int m0 = blockIdx.y * BM, n0 = blockIdx.x * BN;

    f4v acc[MI][NI] = {};

    for (int k0 = 0; k0 < K; k0 += BK) {
        __syncthreads();
#pragma unroll
        for (int i = 0; i < AITER; ++i) {
            int c = (i * 4 + w) * 64 + l;
            int row = c >> 2, ko = (c & 3) * 8;
            glds16(&A[(size_t)(m0 + row) * K + k0 + ko], &As[c * 8]);
        }
#pragma unroll
        for (int i = 0; i < BITER; ++i) {
            int c = (i * 4 + w) * 64 + l;
            int row = c >> 2, ko = (c & 3) * 8;
            glds16(&BT[(size_t)(n0 + row) * K + k0 + ko], &Bs[c * 8]);
        }
        __syncthreads();
        s8v a[MI], b[NI];
#pragma unroll
        for (int mi = 0; mi < MI; ++mi)
            a[mi] = *(const s8v*)&As[(wm * (BM / 2) + mi * 16 + r16) * BK + q * 8];
#pragma unroll
        for (int ni = 0; ni < NI; ++ni)
            b[ni] = *(const s8v*)&Bs[(wn * (BN / 2) + ni * 16 + r16) * BK + q * 8];
#pragma unroll
        for (int mi = 0; mi < MI; ++mi)
#pragma unroll
            for (int ni = 0; ni < NI; ++ni)
                acc[mi][ni] = __builtin_amdgcn_mfma_f32_16x16x32_bf16(a[mi], b[ni], acc[mi][ni], 0, 0, 0);
    }
#pragma unroll
    for (int mi = 0; mi < MI; ++mi)
#pragma unroll
        for (int ni = 0; ni < NI; ++ni) {
            int col = n0 + wn * (BN / 2) + ni * 16 + r16;
            float bv = bias[col];
#pragma unroll
            for (int r = 0; r < 4; ++r) {
                int row = m0 + wm * (BM / 2) + mi * 16 + q * 4 + r;
                C[(size_t)row * N + col] = f2b(tanhf(acc[mi][ni][r] + bv));
            }
        }
}

// ---------- kernel 5: final layer, N=1: out = sigmoid(h4 @ w5 + b5) ----------
__global__ void layer5(const unsigned short* __restrict__ h4, const unsigned short* __restrict__ w5,
                       const float* __restrict__ b5, float* __restrict__ out) {
    int row = blockIdx.x * 4 + (threadIdx.x >> 6);
    int l = threadIdx.x & 63;
    const ushort4 hv = *(const ushort4*)(h4 + (size_t)row * 256 + l * 4);
    const ushort4 wv = *(const ushort4*)(w5 + l * 4);
    float s = b2f(hv.x) * b2f(wv.x) + b2f(hv.y) * b2f(wv.y)
            + b2f(hv.z) * b2f(wv.z) + b2f(hv.w) * b2f(wv.w);
#pragma unroll
    for (int off = 32; off > 0; off >>= 1) s += __shfl_down(s, off);
    if (l == 0) out[row] = 1.0f / (1.0f + expf(-(s + b5[0])));
}

extern "C" void kernel_launch(void* const* d_in, const int* in_sizes, int n_in,
                              void* d_out, int out_size, void* d_ws, size_t ws_size,
                              hipStream_t stream) {
    const float* H  = (const float*)d_in[0];
    const float* Ro = (const float*)d_in[1];
    const float* Ri = (const float*)d_in[2];
    const float* e  = (const float*)d_in[3];
    const float* W1 = (const float*)d_in[4];  const float* b1 = (const float*)d_in[5];
    const float* W2 = (const float*)d_in[6];  const float* b2 = (const float*)d_in[7];
    const float* W3 = (const float*)d_in[8];  const float* b3 = (const float*)d_in[9];
    const float* W4 = (const float*)d_in[10]; const float* b4 = (const float*)d_in[11];
    const float* W5 = (const float*)d_in[12]; const float* b5 = (const float*)d_in[13];
    float* out = (float*)d_out;

    char* p = (char*)d_ws;
    auto alloc = [&](size_t bytes) -> void* {
        void* r = (void*)p;
        p += (bytes + 255) & ~(size_t)255;
        return r;
    };
    float* xf = (float*)alloc((size_t)N_NODES * 256 * 4);            // [Ho|Hi] f32, 4 MB
    unsigned short* h1  = (unsigned short*)alloc((size_t)N_NODES * HID * 2);
    unsigned short* h2  = (unsigned short*)alloc((size_t)N_NODES * HID * 2);
    unsigned short* h3  = (unsigned short*)alloc((size_t)N_NODES * (HID / 2) * 2);
    unsigned short* h4  = (unsigned short*)alloc((size_t)N_NODES * (HID / 4) * 2);
    unsigned short* wt1 = (unsigned short*)alloc((size_t)HID * 384 * 2);
    unsigned short* wt2 = (unsigned short*)alloc((size_t)HID * HID * 2);
    unsigned short* wt3 = (unsigned short*)alloc((size_t)(HID / 2) * HID * 2);
    unsigned short* wt4 = (unsigned short*)alloc((size_t)(HID / 4) * (HID / 2) * 2);
    unsigned short* wt5 = (unsigned short*)alloc((size_t)(HID / 4) * 2);

    // 1) zero Ho/Hi accumulator
    hipMemsetAsync(xf, 0, (size_t)N_NODES * 256 * 4, stream);

    // 2) fused extract + scatter (~278 MB read + 4.2M f32 atomics)
    extract_scatter<<<N_EDGES / 4, 256, 0, stream>>>(Ro, Ri, H, e, xf);

    // 3) weight transpose+convert
    wtrans_all<<<2049, 256, 0, stream>>>(W1, wt1, W2, wt2, W3, wt3, W4, wt4, W5, wt5);

    // 4) MLP (all >=2 blocks/CU except L4 at 1)
    gemm1<<<dim3(HID / L1_BN, N_NODES / L1_BM), 256, 0, stream>>>(xf, H, wt1, b1, h1);
    gemm_tanh<128, 64><<<dim3(HID / 64, N_NODES / 128), 256, 0, stream>>>(h1, wt2, b2, h2, N_NODES, HID, HID);
    gemm_tanh<64, 64><<<dim3((HID / 2) / 64, N_NODES / 64), 256, 0, stream>>>(h2, wt3, b3, h3, N_NODES, HID / 2, HID);
    gemm_tanh<64, 64><<<dim3((HID / 4) / 64, N_NODES / 64), 256, 0, stream>>>(h3, wt4, b4, h4, N_NODES, HID / 4, HID / 2);

    // 5) final sigmoid layer
    layer5<<<N_NODES / 4, 256, 0, stream>>>(h4, wt5, b5, out);
}

// Round 6
// 569.732 us; speedup vs baseline: 1.1881x; 1.0126x over previous
//
#include <hip/hip_runtime.h>
#include <hip/hip_bf16.h>
#include <math.h>

#define N_NODES 4096
#define N_EDGES 16384
#define D_IN 128
#define HID 1024

typedef short s8v __attribute__((ext_vector_type(8)));
typedef float f4v __attribute__((ext_vector_type(4)));

// ---------- helpers ----------
__device__ __forceinline__ unsigned short f2b(float v) {
    union { float f; unsigned int u; } c; c.f = v;
    unsigned int u = c.u + 0x7fffu + ((c.u >> 16) & 1u);  // round-to-nearest-even
    return (unsigned short)(u >> 16);
}
__device__ __forceinline__ float b2f(unsigned short b) {
    union { unsigned int u; float f; } c; c.u = ((unsigned int)b) << 16;
    return c.f;
}
__device__ __forceinline__ void glds16(const unsigned short* g, unsigned short* l) {
    __builtin_amdgcn_global_load_lds(
        (const __attribute__((address_space(1))) void*)g,
        (__attribute__((address_space(3))) void*)l, 16, 0, 0);
}

// ---------- kernel 1: fused index-extract + scatter ----------
// wave per edge: ballot early-exit scan of Ro/Ri rows (256-col granularity,
// ~278 MB expected; nontemporal loads — zero reuse, keep H/weights in L2),
// then f32 atomic scatter. xf [N_NODES][256]: cols 0..127 = Ho, 128..255 = Hi.
__global__ void extract_scatter(const float* __restrict__ Ro, const float* __restrict__ Ri,
                                const float* __restrict__ H, const float* __restrict__ e,
                                float* __restrict__ xf) {
    int edge = (blockIdx.x * 256 + threadIdx.x) >> 6;
    int l = threadIdx.x & 63;
    const f4v* ro4 = (const f4v*)(Ro + (size_t)edge * N_NODES);
    const f4v* ri4 = (const f4v*)(Ri + (size_t)edge * N_NODES);
    int src = -1, dst = -1;
    for (int it = 0; it < 16; ++it) {
        if (src < 0) {
            f4v v = __builtin_nontemporal_load(&ro4[it * 64 + l]);
            bool hit = (v.x != 0.0f) | (v.y != 0.0f) | (v.z != 0.0f) | (v.w != 0.0f);
            unsigned long long m = __ballot(hit);
            if (m) {
                int fl = __ffsll((long long)m) - 1;
                int idx = 0;
                if (hit) idx = (it * 64 + l) * 4 + (v.x != 0.0f ? 0 : v.y != 0.0f ? 1 : v.z != 0.0f ? 2 : 3);
                src = __shfl(idx, fl);
            }
        }
        if (dst < 0) {
            f4v v = __builtin_nontemporal_load(&ri4[it * 64 + l]);
            bool hit = (v.x != 0.0f) | (v.y != 0.0f) | (v.z != 0.0f) | (v.w != 0.0f);
            unsigned long long m = __ballot(hit);
            if (m) {
                int fl = __ffsll((long long)m) - 1;
                int idx = 0;
                if (hit) idx = (it * 64 + l) * 4 + (v.x != 0.0f ? 0 : v.y != 0.0f ? 1 : v.z != 0.0f ? 2 : 3);
                dst = __shfl(idx, fl);
            }
        }
        if (src >= 0 && dst >= 0) break;
    }
    float es = e[src], ed = e[dst];
    if (l < 32) {            // Ho[dst] += es * H[src]
        int f = l * 4;
        float4 h = *(const float4*)(H + (size_t)src * 128 + f);
        float* o = xf + (size_t)dst * 256 + f;
        atomicAdd(o + 0, es * h.x); atomicAdd(o + 1, es * h.y);
        atomicAdd(o + 2, es * h.z); atomicAdd(o + 3, es * h.w);
    } else {                 // Hi[src] += ed * H[dst]
        int f = (l - 32) * 4;
        float4 h = *(const float4*)(H + (size_t)dst * 128 + f);
        float* o = xf + (size_t)src * 256 + 128 + f;
        atomicAdd(o + 0, ed * h.x); atomicAdd(o + 1, ed * h.y);
        atomicAdd(o + 2, ed * h.z); atomicAdd(o + 3, ed * h.w);
    }
}

// ---------- kernel 2: weight transpose+convert (W1..W4) + zero xf ----------
// blocks 0..2047: 32x32 transpose tiles; blocks 2048..2559: zero 2048 floats of xf each.
__global__ void wtrans_zero(const float* __restrict__ W1, unsigned short* __restrict__ wt1,
                            const float* __restrict__ W2, unsigned short* __restrict__ wt2,
                            const float* __restrict__ W3, unsigned short* __restrict__ wt3,
                            const float* __restrict__ W4, unsigned short* __restrict__ wt4,
                            float* __restrict__ xf) {
    int b = blockIdx.x, t = threadIdx.x;
    if (b >= 2048) {  // zero xf: 512 blocks x 2048 floats
        float4 z = {0.f, 0.f, 0.f, 0.f};
        float4* o = (float4*)(xf + (size_t)(b - 2048) * 2048) + t;
        o[0] = z; o[256] = z;
        return;
    }
    const float* W; unsigned short* WT; int K, N, tb;
    if (b < 384)       { W = W1; WT = wt1; K = 384;  N = 1024; tb = b; }
    else if (b < 1408) { W = W2; WT = wt2; K = 1024; N = 1024; tb = b - 384; }
    else if (b < 1920) { W = W3; WT = wt3; K = 1024; N = 512;  tb = b - 1408; }
    else               { W = W4; WT = wt4; K = 512;  N = 256;  tb = b - 1920; }

    __shared__ float tile[32][33];
    int ntx = N >> 5;
    int tk = tb / ntx, tn = tb - tk * ntx;
    int tr = t >> 5, tc = t & 31;
#pragma unroll
    for (int i = 0; i < 4; ++i)
        tile[tr + i * 8][tc] = W[(size_t)(tk * 32 + tr + i * 8) * N + tn * 32 + tc];
    __syncthreads();
#pragma unroll
    for (int i = 0; i < 4; ++i)
        WT[(size_t)(tn * 32 + tr + i * 8) * K + tk * 32 + tc] = f2b(tile[tc][tr + i * 8]);
}

// ---------- kernel 3: layer-1 GEMM, A staged from f32 (xf|H) with inline cvt ----------
#define L1_BM 128
#define L1_BN 64
__global__ __launch_bounds__(256)
void gemm1(const float* __restrict__ xf, const float* __restrict__ H,
           const unsigned short* __restrict__ BT, const float* __restrict__ bias,
           unsigned short* __restrict__ C) {
    constexpr int BK = 32, K = 384, N = HID;
    constexpr int MI = L1_BM / 32, NI = L1_BN / 32;
    __shared__ unsigned short As[L1_BM * BK];
    __shared__ unsigned short Bs[L1_BN * BK];
    int t = threadIdx.x;
    int l = t & 63, w = t >> 6;
    int wm = w >> 1, wn = w & 1;
    int q = l >> 4, r16 = l & 15;
    int m0 = blockIdx.y * L1_BM, n0 = blockIdx.x * L1_BN;

    f4v acc[MI][NI] = {};

    for (int k0 = 0; k0 < K; k0 += BK) {
        __syncthreads();
#pragma unroll
        for (int i = 0; i < 2; ++i) {
            int c = i * 256 + t;
            int row = c >> 2, ko = (c & 3) * 8;
            const float* sp;
            if (k0 < 128)      sp = xf + (size_t)(m0 + row) * 256 + k0 + ko;
            else if (k0 < 256) sp = H + (size_t)(m0 + row) * 128 + (k0 - 128) + ko;
            else               sp = xf + (size_t)(m0 + row) * 256 + (k0 - 128) + ko;
            float4 f0 = *(const float4*)sp, f1 = *(const float4*)(sp + 4);
            s8v pk;
            pk[0] = (short)f2b(f0.x); pk[1] = (short)f2b(f0.y);
            pk[2] = (short)f2b(f0.z); pk[3] = (short)f2b(f0.w);
            pk[4] = (short)f2b(f1.x); pk[5] = (short)f2b(f1.y);
            pk[6] = (short)f2b(f1.z); pk[7] = (short)f2b(f1.w);
            *(s8v*)&As[c * 8] = pk;
        }
        {
            int c = w * 64 + l;
            int row = c >> 2, ko = (c & 3) * 8;
            glds16(&BT[(size_t)(n0 + row) * K + k0 + ko], &Bs[c * 8]);
        }
        __syncthreads();
        s8v a[MI], b[NI];
#pragma unroll
        for (int mi = 0; mi < MI; ++mi)
            a[mi] = *(const s8v*)&As[(wm * (L1_BM / 2) + mi * 16 + r16) * BK + q * 8];
#pragma unroll
        for (int ni = 0; ni < NI; ++ni)
            b[ni] = *(const s8v*)&Bs[(wn * (L1_BN / 2) + ni * 16 + r16) * BK + q * 8];
#pragma unroll
        for (int mi = 0; mi < MI; ++mi)
#pragma unroll
            for (int ni = 0; ni < NI; ++ni)
                acc[mi][ni] = __builtin_amdgcn_mfma_f32_16x16x32_bf16(a[mi], b[ni], acc[mi][ni], 0, 0, 0);
    }
#pragma unroll
    for (int mi = 0; mi < MI; ++mi)
#pragma unroll
        for (int ni = 0; ni < NI; ++ni) {
            int col = n0 + wn * (L1_BN / 2) + ni * 16 + r16;
            float bv = bias[col];
#pragma unroll
            for (int r = 0; r < 4; ++r) {
                int row = m0 + wm * (L1_BM / 2) + mi * 16 + q * 4 + r;
                C[(size_t)row * N + col] = f2b(tanhf(acc[mi][ni][r] + bv));
            }
        }
}

// ---------- kernel 4: bf16 MFMA GEMM (m97-style), C = tanh(A @ BT^T + bias) ----------
template<int BM, int BN>
__global__ __launch_bounds__(256)
void gemm_tanh(const unsigned short* __restrict__ A, const unsigned short* __restrict__ BT,
               const float* __restrict__ bias, unsigned short* __restrict__ C,
               int M, int N, int K) {
    constexpr int BK = 32;
    constexpr int MI = BM / 32, NI = BN / 32;
    constexpr int AITER = BM / 64, BITER = BN / 64;
    __shared__ unsigned short As[BM * BK];
    __shared__ unsigned short Bs[BN * BK];
    int t = threadIdx.x;
    int l = t & 63, w = t >> 6;
    int wm = w >> 1, wn = w & 1;
    int q = l >> 4, r16 = l & 15;
    int m0 = blockIdx.y * BM, n0 = blockIdx.x * BN;

    f4v acc[MI][NI] = {};

    for (int k0 = 0; k0 < K; k0 += BK) {
        __syncthreads();
#pragma unroll
        for (int i = 0; i < AITER; ++i) {
            int c = (i * 4 + w) * 64 + l;
            int row = c >> 2, ko = (c & 3) * 8;
            glds16(&A[(size_t)(m0 + row) * K + k0 + ko], &As[c * 8]);
        }
#pragma unroll
        for (int i = 0; i < BITER; ++i) {
            int c = (i * 4 + w) * 64 + l;
            int row = c >> 2, ko = (c & 3) * 8;
            glds16(&BT[(size_t)(n0 + row) * K + k0 + ko], &Bs[c * 8]);
        }
        __syncthreads();
        s8v a[MI], b[NI];
#pragma unroll
        for (int mi = 0; mi < MI; ++mi)
            a[mi] = *(const s8v*)&As[(wm * (BM / 2) + mi * 16 + r16) * BK + q * 8];
#pragma unroll
        for (int ni = 0; ni < NI; ++ni)
            b[ni] = *(const s8v*)&Bs[(wn * (BN / 2) + ni * 16 + r16) * BK + q * 8];
#pragma unroll
        for (int mi = 0; mi < MI; ++mi)
#pragma unroll
            for (int ni = 0; ni < NI; ++ni)
                acc[mi][ni] = __builtin_amdgcn_mfma_f32_16x16x32_bf16(a[mi], b[ni], acc[mi][ni], 0, 0, 0);
    }
#pragma unroll
    for (int mi = 0; mi < MI; ++mi)
#pragma unroll
        for (int ni = 0; ni < NI; ++ni) {
            int col = n0 + wn * (BN / 2) + ni * 16 + r16;
            float bv = bias[col];
#pragma unroll
            for (int r = 0; r < 4; ++r) {
                int row = m0 + wm * (BM / 2) + mi * 16 + q * 4 + r;
                C[(size_t)row * N + col] = f2b(tanhf(acc[mi][ni][r] + bv));
            }
        }
}

// ---------- kernel 5: fused L4+L5 ----------
// h4 = tanh(h3 @ wt4^T + b4)  [4096,256], out = sigmoid(h4 @ W5 + b5)  [4096]
// BM=32, BN=256 (full width), BK=32, K=512. 4 waves 2x2: wave tile 16x128.
__global__ __launch_bounds__(256)
void gemm45(const unsigned short* __restrict__ A, const unsigned short* __restrict__ BT,
            const float* __restrict__ b4, const float* __restrict__ W5,
            const float* __restrict__ b5, float* __restrict__ out) {
    constexpr int BK = 32, K = 512, NN = 256;
    constexpr int NI = 8;
    __shared__ unsigned short As[32 * BK];
    __shared__ unsigned short Bs[NN * BK];
    __shared__ float part[32][2];
    int t = threadIdx.x;
    int l = t & 63, w = t >> 6;
    int wm = w >> 1, wn = w & 1;
    int q = l >> 4, r16 = l & 15;
    int m0 = blockIdx.y * 32;

    f4v acc[NI] = {};

    for (int k0 = 0; k0 < K; k0 += BK) {
        __syncthreads();
        if (w < 2) {
            int c = w * 64 + l;
            int row = c >> 2, ko = (c & 3) * 8;
            glds16(&A[(size_t)(m0 + row) * K + k0 + ko], &As[c * 8]);
        }
#pragma unroll
        for (int i = 0; i < 4; ++i) {
            int c = (i * 4 + w) * 64 + l;
            int row = c >> 2, ko = (c & 3) * 8;
            glds16(&BT[(size_t)row * K + k0 + ko], &Bs[c * 8]);
        }
        __syncthreads();
        s8v a = *(const s8v*)&As[(wm * 16 + r16) * BK + q * 8];
        s8v b[NI];
#pragma unroll
        for (int ni = 0; ni < NI; ++ni)
            b[ni] = *(const s8v*)&Bs[(wn * 128 + ni * 16 + r16) * BK + q * 8];
#pragma unroll
        for (int ni = 0; ni < NI; ++ni)
            acc[ni] = __builtin_amdgcn_mfma_f32_16x16x32_bf16(a, b[ni], acc[ni], 0, 0, 0);
    }

    float partial[4] = {0.f, 0.f, 0.f, 0.f};
#pragma unroll
    for (int ni = 0; ni < NI; ++ni) {
        int col = wn * 128 + ni * 16 + r16;
        float bv = b4[col], wv = W5[col];
#pragma unroll
        for (int r = 0; r < 4; ++r)
            partial[r] += tanhf(acc[ni][r] + bv) * wv;
    }
#pragma unroll
    for (int off = 1; off < 16; off <<= 1)
#pragma unroll
        for (int r = 0; r < 4; ++r)
            partial[r] += __shfl_xor(partial[r], off);
    if (r16 == 0)
#pragma unroll
        for (int r = 0; r < 4; ++r)
            part[wm * 16 + q * 4 + r][wn] = partial[r];
    __syncthreads();
    if (t < 32) {
        float s = part[t][0] + part[t][1] + b5[0];
        out[m0 + t] = 1.0f / (1.0f + expf(-s));
    }
}

extern "C" void kernel_launch(void* const* d_in, const int* in_sizes, int n_in,
                              void* d_out, int out_size, void* d_ws, size_t ws_size,
                              hipStream_t stream) {
    const float* H  = (const float*)d_in[0];
    const float* Ro = (const float*)d_in[1];
    const float* Ri = (const float*)d_in[2];
    const float* e  = (const float*)d_in[3];
    const float* W1 = (const float*)d_in[4];  const float* b1 = (const float*)d_in[5];
    const float* W2 = (const float*)d_in[6];  const float* b2 = (const float*)d_in[7];
    const float* W3 = (const float*)d_in[8];  const float* b3 = (const float*)d_in[9];
    const float* W4 = (const float*)d_in[10]; const float* b4 = (const float*)d_in[11];
    const float* W5 = (const float*)d_in[12]; const float* b5 = (const float*)d_in[13];
    float* out = (float*)d_out;

    char* p = (char*)d_ws;
    auto alloc = [&](size_t bytes) -> void* {
        void* r = (void*)p;
        p += (bytes + 255) & ~(size_t)255;
        return r;
    };
    float* xf = (float*)alloc((size_t)N_NODES * 256 * 4);            // [Ho|Hi] f32, 4 MB
    unsigned short* h1  = (unsigned short*)alloc((size_t)N_NODES * HID * 2);
    unsigned short* h2  = (unsigned short*)alloc((size_t)N_NODES * HID * 2);
    unsigned short* h3  = (unsigned short*)alloc((size_t)N_NODES * (HID / 2) * 2);
    unsigned short* wt1 = (unsigned short*)alloc((size_t)HID * 384 * 2);
    unsigned short* wt2 = (unsigned short*)alloc((size_t)HID * HID * 2);
    unsigned short* wt3 = (unsigned short*)alloc((size_t)(HID / 2) * HID * 2);
    unsigned short* wt4 = (unsigned short*)alloc((size_t)(HID / 4) * (HID / 2) * 2);

    // 1) weight transpose+convert + xf zeroing (one dispatch)
    wtrans_zero<<<2560, 256, 0, stream>>>(W1, wt1, W2, wt2, W3, wt3, W4, wt4, xf);

    // 2) fused extract + scatter (~278 MB nt read + 4.2M f32 atomics)
    extract_scatter<<<N_EDGES / 4, 256, 0, stream>>>(Ro, Ri, H, e, xf);

    // 3) MLP
    gemm1<<<dim3(HID / L1_BN, N_NODES / L1_BM), 256, 0, stream>>>(xf, H, wt1, b1, h1);
    gemm_tanh<128, 64><<<dim3(HID / 64, N_NODES / 128), 256, 0, stream>>>(h1, wt2, b2, h2, N_NODES, HID, HID);
    gemm_tanh<64, 64><<<dim3((HID / 2) / 64, N_NODES / 64), 256, 0, stream>>>(h2, wt3, b3, h3, N_NODES, HID / 2, HID);

    // 4) fused L4+L5 -> sigmoid out
    gemm45<<<dim3(1, N_NODES / 32), 256, 0, stream>>>(h3, wt4, b4, W5, b5, out);
}